// Round 1
// baseline (1791.071 us; speedup 1.0000x reference)
//
#include <hip/hip_runtime.h>
#include <float.h>
#include <math.h>

#define NROWS 512
#define DIM 1024
#define NTRAIN 100000
#define MAXK 200
#define NCLS 1000
#define CAP 512       // candidate cap per row (>= 200 + tie slack)
#define BBCAP 3072    // boundary-bin buffer cap
#define INV_T (1.0f/0.07f)

// monotone float -> uint key (ascending key <=> ascending float)
__device__ __forceinline__ unsigned fkey(float f) {
    unsigned u = __float_as_uint(f);
    return (u & 0x80000000u) ? ~u : (u | 0x80000000u);
}

// ---------------- GEMM: sims[512][chunk] = A[512][1024] * B[chunk][1024]^T ----------------
__global__ __launch_bounds__(256) void gemm_chunk(
    const float* __restrict__ A, const float* __restrict__ B,
    float* __restrict__ sims, int chunk_start, int cvalid, int sstride)
{
    __shared__ float As[16][128];
    __shared__ float Bs[16][128];
    const int tid = threadIdx.x;
    const int m0 = blockIdx.y * 128;
    const int n0 = blockIdx.x * 128;
    const int tx = tid & 15, ty = tid >> 4;

    float acc[8][8];
    #pragma unroll
    for (int i = 0; i < 8; ++i)
        #pragma unroll
        for (int j = 0; j < 8; ++j) acc[i][j] = 0.f;

    for (int k0 = 0; k0 < DIM; k0 += 16) {
        // stage A,B tiles (transposed into [k][m]/[k][n])
        #pragma unroll
        for (int it = 0; it < 2; ++it) {
            int i = tid + it * 256;
            int kq = i & 3, row = i >> 2;   // row in 0..127, kq = float4 along K
            const float4 va = *reinterpret_cast<const float4*>(
                &A[(size_t)(m0 + row) * DIM + k0 + kq * 4]);
            As[kq*4+0][row] = va.x; As[kq*4+1][row] = va.y;
            As[kq*4+2][row] = va.z; As[kq*4+3][row] = va.w;
            float4 vb = make_float4(0.f, 0.f, 0.f, 0.f);
            int nl = n0 + row;
            if (nl < cvalid)
                vb = *reinterpret_cast<const float4*>(
                    &B[(size_t)(chunk_start + nl) * DIM + k0 + kq * 4]);
            Bs[kq*4+0][row] = vb.x; Bs[kq*4+1][row] = vb.y;
            Bs[kq*4+2][row] = vb.z; Bs[kq*4+3][row] = vb.w;
        }
        __syncthreads();
        #pragma unroll
        for (int kk = 0; kk < 16; ++kk) {
            const float4 a0 = *reinterpret_cast<const float4*>(&As[kk][ty*8]);
            const float4 a1 = *reinterpret_cast<const float4*>(&As[kk][ty*8+4]);
            const float4 b0 = *reinterpret_cast<const float4*>(&Bs[kk][tx*8]);
            const float4 b1 = *reinterpret_cast<const float4*>(&Bs[kk][tx*8+4]);
            float av[8] = {a0.x,a0.y,a0.z,a0.w,a1.x,a1.y,a1.z,a1.w};
            float bv[8] = {b0.x,b0.y,b0.z,b0.w,b1.x,b1.y,b1.z,b1.w};
            #pragma unroll
            for (int i = 0; i < 8; ++i)
                #pragma unroll
                for (int j = 0; j < 8; ++j)
                    acc[i][j] = fmaf(av[i], bv[j], acc[i][j]);
        }
        __syncthreads();
    }

    // store
    const int nbase = n0 + tx * 8;
    #pragma unroll
    for (int i = 0; i < 8; ++i) {
        int row = m0 + ty * 8 + i;
        float* orow = sims + (size_t)row * sstride + nbase;
        if (nbase + 7 < cvalid) {
            *reinterpret_cast<float4*>(&orow[0]) =
                make_float4(acc[i][0], acc[i][1], acc[i][2], acc[i][3]);
            *reinterpret_cast<float4*>(&orow[4]) =
                make_float4(acc[i][4], acc[i][5], acc[i][6], acc[i][7]);
        } else {
            for (int j = 0; j < 8; ++j)
                if (nbase + j < cvalid) orow[j] = acc[i][j];
        }
    }
}

// ---------------- per-row top-200 superset selection (radix, 11+11 bits) ----------------
__global__ __launch_bounds__(256) void select_topk(
    const float* __restrict__ sims, int sstride, int chunk_start, int cvalid,
    const float* __restrict__ pv, const int* __restrict__ pi, const int* __restrict__ pc,
    float* __restrict__ nv, int* __restrict__ ni, int* __restrict__ nc, int have_prev)
{
    __shared__ int hist[2048];
    __shared__ float bbv[BBCAP];
    __shared__ int bbi[BBCAP];
    __shared__ int s_binB, s_above, s_ccnt, s_bcnt, s_binB2;
    const int tid = threadIdx.x;
    const int r = blockIdx.x;
    const int pcnt = have_prev ? pc[r] : 0;
    const int total = cvalid + pcnt;
    const float* srow = sims + (size_t)r * sstride;
    const float* pvr = pv + (size_t)r * CAP;
    const int*   pir = pi + (size_t)r * CAP;

    for (int i = tid; i < 2048; i += 256) hist[i] = 0;
    if (tid == 0) { s_ccnt = 0; s_bcnt = 0; }
    __syncthreads();

    // level-1 histogram over top 11 key bits
    for (int i = tid; i < total; i += 256) {
        float v = (i < cvalid) ? srow[i] : pvr[i - cvalid];
        atomicAdd(&hist[fkey(v) >> 21], 1);
    }
    __syncthreads();
    if (tid == 0) {
        int cum = 0, b = 2047;
        for (; b > 0; --b) {
            if (cum + hist[b] >= MAXK) break;
            cum += hist[b];
        }
        s_binB = b; s_above = cum;
    }
    __syncthreads();
    const int binB = s_binB;

    // pass 2: emit strictly-above bins; stash boundary bin
    for (int i = tid; i < total; i += 256) {
        float v; int idx;
        if (i < cvalid) { v = srow[i]; idx = chunk_start + i; }
        else { v = pvr[i - cvalid]; idx = pir[i - cvalid]; }
        int b = (int)(fkey(v) >> 21);
        if (b > binB) {
            int p = atomicAdd(&s_ccnt, 1);
            if (p < CAP) { nv[(size_t)r*CAP + p] = v; ni[(size_t)r*CAP + p] = idx; }
        } else if (b == binB) {
            int p = atomicAdd(&s_bcnt, 1);
            if (p < BBCAP) { bbv[p] = v; bbi[p] = idx; }
        }
    }
    __syncthreads();
    const int bcnt = min(s_bcnt, BBCAP);
    const int need = MAXK - s_above;   // >= 1

    // level-2 refine within boundary bin (next 11 bits)
    for (int i = tid; i < 2048; i += 256) hist[i] = 0;
    __syncthreads();
    for (int i = tid; i < bcnt; i += 256)
        atomicAdd(&hist[(fkey(bbv[i]) >> 10) & 0x7FF], 1);
    __syncthreads();
    if (tid == 0) {
        int cum = 0, b = 2047;
        for (; b > 0; --b) {
            if (cum + hist[b] >= need) break;
            cum += hist[b];
        }
        s_binB2 = b;
    }
    __syncthreads();
    const int binB2 = s_binB2;
    for (int i = tid; i < bcnt; i += 256) {
        int sub = (int)((fkey(bbv[i]) >> 10) & 0x7FF);
        if (sub >= binB2) {
            int p = atomicAdd(&s_ccnt, 1);
            if (p < CAP) { nv[(size_t)r*CAP + p] = bbv[i]; ni[(size_t)r*CAP + p] = bbi[i]; }
        }
    }
    __syncthreads();
    if (tid == 0) nc[r] = min(s_ccnt, CAP);
}

// ---------------- final: sort candidates, softmax over top-200, scatter 4 slabs ----------------
__global__ __launch_bounds__(256) void finalize_knn(
    const float* __restrict__ cv, const int* __restrict__ ci, const int* __restrict__ cc,
    const int* __restrict__ labels, float* __restrict__ out)
{
    __shared__ float sval[CAP];
    __shared__ int   sidx[CAP];
    __shared__ float cls[NCLS];
    __shared__ float s_sum;
    const int tid = threadIdx.x;
    const int r = blockIdx.x;
    const int M = min(cc[r], CAP);

    for (int i = tid; i < CAP; i += 256) {
        if (i < M) { sval[i] = cv[(size_t)r*CAP + i]; sidx[i] = ci[(size_t)r*CAP + i]; }
        else { sval[i] = -FLT_MAX; sidx[i] = 0x7FFFFFFF; }
    }
    __syncthreads();

    // bitonic sort, descending by (val desc, idx asc)
    for (int k = 2; k <= CAP; k <<= 1) {
        for (int j = k >> 1; j > 0; j >>= 1) {
            for (int i = tid; i < CAP; i += 256) {
                int l = i ^ j;
                if (l > i) {
                    float av = sval[i], bv = sval[l];
                    int ai = sidx[i], bi = sidx[l];
                    bool iGTl = (av > bv) || (av == bv && ai < bi);
                    bool sw = ((i & k) == 0) ? (!iGTl) : iGTl;
                    if (sw) { sval[i] = bv; sval[l] = av; sidx[i] = bi; sidx[l] = ai; }
                }
            }
            __syncthreads();
        }
    }

    // softmax over first MAXK (max is sval[0])
    float mx = sval[0];
    if (tid == 0) s_sum = 0.f;
    __syncthreads();
    float part = 0.f;
    for (int i = tid; i < MAXK; i += 256) {
        float e = expf((sval[i] - mx) * INV_T);
        sval[i] = e;
        part += e;
    }
    atomicAdd(&s_sum, part);
    __syncthreads();
    float inv = 1.f / s_sum;
    for (int i = tid; i < MAXK; i += 256) {
        sval[i] *= inv;
        sidx[i] = labels[sidx[i]];   // replace index with its class label
    }
    for (int c = tid; c < NCLS; c += 256) cls[c] = 0.f;
    __syncthreads();

    // cumulative prefix scatter: k = 10, 20, 100, 200
    const int KS[4] = {10, 20, 100, 200};
    int prev = 0;
    for (int s = 0; s < 4; ++s) {
        for (int i = prev + tid; i < KS[s]; i += 256)
            atomicAdd(&cls[sidx[i]], sval[i]);
        __syncthreads();
        float* o = out + ((size_t)s * NROWS + r) * NCLS;
        for (int c = tid; c < NCLS; c += 256) o[c] = cls[c];
        __syncthreads();
        prev = KS[s];
    }
}

// ---------------- host launcher ----------------
extern "C" void kernel_launch(void* const* d_in, const int* in_sizes, int n_in,
                              void* d_out, int out_size, void* d_ws, size_t ws_size,
                              hipStream_t stream)
{
    const float* A = (const float*)d_in[0];       // [512,1024]
    const float* B = (const float*)d_in[1];       // [100000,1024]
    const int* labels = (const int*)d_in[2];      // [100000]
    float* out = (float*)d_out;                   // [4,512,1000] f32

    char* ws = (char*)d_ws;
    size_t off = 0;
    auto carve = [&](size_t bytes) -> void* {
        void* p = ws + off;
        off = (off + bytes + 255) & ~(size_t)255;
        return p;
    };
    float* cv0 = (float*)carve((size_t)NROWS * CAP * sizeof(float));
    float* cv1 = (float*)carve((size_t)NROWS * CAP * sizeof(float));
    int*   ci0 = (int*)carve((size_t)NROWS * CAP * sizeof(int));
    int*   ci1 = (int*)carve((size_t)NROWS * CAP * sizeof(int));
    int*   cc0 = (int*)carve((size_t)NROWS * sizeof(int));
    int*   cc1 = (int*)carve((size_t)NROWS * sizeof(int));
    float* sims = (float*)(ws + off);
    size_t remain = (ws_size > off) ? (ws_size - off) : 0;

    long long chunk_ll = (long long)(remain / ((size_t)NROWS * sizeof(float)));
    int chunk = (chunk_ll > NTRAIN) ? NTRAIN : (int)chunk_ll;
    chunk &= ~3;                 // keep float4-aligned row stride
    if (chunk < 256) chunk = 256;   // minimum viable; ws expected to be larger
    if (chunk > NTRAIN) chunk = NTRAIN;

    float* cvs[2] = {cv0, cv1};
    int*   cis[2] = {ci0, ci1};
    int*   ccs[2] = {cc0, cc1};
    int cur = 0, have_prev = 0;

    for (int start = 0; start < NTRAIN; start += chunk) {
        int cvalid = (NTRAIN - start < chunk) ? (NTRAIN - start) : chunk;
        dim3 grid((cvalid + 127) / 128, NROWS / 128);
        gemm_chunk<<<grid, 256, 0, stream>>>(A, B, sims, start, cvalid, chunk);
        select_topk<<<NROWS, 256, 0, stream>>>(sims, chunk, start, cvalid,
            cvs[cur], cis[cur], ccs[cur],
            cvs[cur ^ 1], cis[cur ^ 1], ccs[cur ^ 1], have_prev);
        cur ^= 1;
        have_prev = 1;
    }
    finalize_knn<<<NROWS, 256, 0, stream>>>(cvs[cur], cis[cur], ccs[cur], labels, out);
}

// Round 2
// 1089.017 us; speedup vs baseline: 1.6447x; 1.6447x over previous
//
#include <hip/hip_runtime.h>
#include <float.h>
#include <math.h>

#define NROWS 512
#define DIM 1024
#define NTRAIN 100000
#define MAXK 200
#define NCLS 1000
#define CAP 512       // candidate cap per row
#define BBCAP 3072    // boundary-bin buffer cap
#define INV_T (1.0f/0.07f)

typedef _Float16 f16x8 __attribute__((ext_vector_type(8)));
typedef _Float16 f16x4 __attribute__((ext_vector_type(4)));
typedef float f32x4 __attribute__((ext_vector_type(4)));

// monotone float -> uint key (ascending key <=> ascending float)
__device__ __forceinline__ unsigned fkey(float f) {
    unsigned u = __float_as_uint(f);
    return (u & 0x80000000u) ? ~u : (u | 0x80000000u);
}

__device__ __forceinline__ void gl_lds16(const void* g, void* l) {
    __builtin_amdgcn_global_load_lds(
        (const __attribute__((address_space(1))) unsigned int*)g,
        (__attribute__((address_space(3))) unsigned int*)l, 16, 0, 0);
}

// ---------------- fp32 -> f16 hi/lo split conversion ----------------
__global__ __launch_bounds__(256) void convert_split(
    const float* __restrict__ in, _Float16* __restrict__ hi,
    _Float16* __restrict__ lo, long long n)
{
    long long i0 = ((long long)blockIdx.x * 256 + threadIdx.x) * 4;
    long long stride = (long long)gridDim.x * 1024;
    for (long long i = i0; i < n; i += stride) {
        float4 v = *reinterpret_cast<const float4*>(&in[i]);
        float vv[4] = {v.x, v.y, v.z, v.w};
        f16x4 h, l;
        #pragma unroll
        for (int j = 0; j < 4; ++j) {
            _Float16 hh = (_Float16)vv[j];
            h[j] = hh;
            l[j] = (_Float16)(vv[j] - (float)hh);
        }
        *reinterpret_cast<f16x4*>(&hi[i]) = h;
        *reinterpret_cast<f16x4*>(&lo[i]) = l;
    }
}

// ---------------- 3-term split GEMM: sims = Ahi*Bhi + Ahi*Blo + Alo*Bhi ----------------
// 128x128 tile, BK=32, 4 waves (each 64x64 = 4x4 frags of 16x16x32 f16 MFMA)
__global__ __launch_bounds__(256) void gemm_f16x3(
    const _Float16* __restrict__ Ahi, const _Float16* __restrict__ Alo,
    const _Float16* __restrict__ Bhi, const _Float16* __restrict__ Blo,
    float* __restrict__ sims, int sstride, int cvalid, int chunk_start,
    int use_filter, const float* __restrict__ L,
    float* __restrict__ cv, int* __restrict__ ci, int* __restrict__ ccnt)
{
    __shared__ __align__(16) _Float16 sAh[128*32];
    __shared__ __align__(16) _Float16 sAl[128*32];
    __shared__ __align__(16) _Float16 sBh[128*32];
    __shared__ __align__(16) _Float16 sBl[128*32];
    const int tid = threadIdx.x;
    const int lane = tid & 63;
    const int wave = tid >> 6;
    const int bid = blockIdx.x;
    const int mt = bid & 3, nt = bid >> 2;   // m-tile fastest for B L2/L3 reuse
    const int m0 = mt * 128, n0 = nt * 128;
    const int wm = wave >> 1, wn = wave & 1;

    // staging lane mapping: issue t covers local rows t*64..t*64+63, 4 lanes/row.
    // XOR-swizzle the GLOBAL k-slot (dest must stay linear for global_load_lds).
    const int r0 = tid >> 2, s0 = tid & 3;
    const int r1 = r0 + 64;
    const int g0 = ((s0 ^ (r0 & 3)) << 3);   // element offset within row (slot*8)
    const int g1 = ((s0 ^ (r1 & 3)) << 3);
    const size_t a0 = (size_t)(m0 + r0) * DIM + g0;
    const size_t a1 = (size_t)(m0 + r1) * DIM + g1;
    const size_t b0 = (size_t)(n0 + r0) * DIM + g0;
    const size_t b1 = (size_t)(n0 + r1) * DIM + g1;
    char* l0 = (char*)nullptr;
    const int lds0 = wave * 1024;
    const int lds1 = 4096 + wave * 1024;

    f32x4 acc[4][4] = {};

    for (int k0 = 0; k0 < DIM; k0 += 32) {
        gl_lds16(Ahi + a0 + k0, (char*)sAh + lds0);
        gl_lds16(Ahi + a1 + k0, (char*)sAh + lds1);
        gl_lds16(Alo + a0 + k0, (char*)sAl + lds0);
        gl_lds16(Alo + a1 + k0, (char*)sAl + lds1);
        gl_lds16(Bhi + b0 + k0, (char*)sBh + lds0);
        gl_lds16(Bhi + b1 + k0, (char*)sBh + lds1);
        gl_lds16(Blo + b0 + k0, (char*)sBl + lds0);
        gl_lds16(Blo + b1 + k0, (char*)sBl + lds1);
        __syncthreads();   // drains vmcnt for global_load_lds

        const int q = lane >> 4;
        const int sl = ((q ^ (lane & 3)) << 3);  // de-swizzle on read
        f16x8 ah[4], al[4], bh[4], bl[4];
        #pragma unroll
        for (int m = 0; m < 4; ++m) {
            int off = (wm*64 + m*16 + (lane & 15)) * 32 + sl;
            ah[m] = *reinterpret_cast<const f16x8*>(&sAh[off]);
            al[m] = *reinterpret_cast<const f16x8*>(&sAl[off]);
        }
        #pragma unroll
        for (int n = 0; n < 4; ++n) {
            int off = (wn*64 + n*16 + (lane & 15)) * 32 + sl;
            bh[n] = *reinterpret_cast<const f16x8*>(&sBh[off]);
            bl[n] = *reinterpret_cast<const f16x8*>(&sBl[off]);
        }
        #pragma unroll
        for (int m = 0; m < 4; ++m)
            #pragma unroll
            for (int n = 0; n < 4; ++n) {
                acc[m][n] = __builtin_amdgcn_mfma_f32_16x16x32_f16(ah[m], bh[n], acc[m][n], 0, 0, 0);
                acc[m][n] = __builtin_amdgcn_mfma_f32_16x16x32_f16(ah[m], bl[n], acc[m][n], 0, 0, 0);
                acc[m][n] = __builtin_amdgcn_mfma_f32_16x16x32_f16(al[m], bh[n], acc[m][n], 0, 0, 0);
            }
        __syncthreads();   // protect LDS before next stage
    }
    (void)l0;

    // epilogue: C/D layout col=lane&15, row=(lane>>4)*4+reg
    const int q4 = (lane >> 4) * 4;
    const int cL = lane & 15;
    if (!use_filter) {
        #pragma unroll
        for (int m = 0; m < 4; ++m)
            #pragma unroll
            for (int j = 0; j < 4; ++j) {
                int orow = m0 + wm*64 + m*16 + q4 + j;
                float* dst = sims + (size_t)orow * sstride + n0 + wn*64 + cL;
                #pragma unroll
                for (int n = 0; n < 4; ++n)
                    dst[n*16] = acc[m][n][j];
            }
    } else {
        #pragma unroll
        for (int m = 0; m < 4; ++m)
            #pragma unroll
            for (int j = 0; j < 4; ++j) {
                int orow = m0 + wm*64 + m*16 + q4 + j;
                float Lr = L[orow];
                #pragma unroll
                for (int n = 0; n < 4; ++n) {
                    float v = acc[m][n][j];
                    int ocol = n0 + wn*64 + n*16 + cL;
                    if (ocol < cvalid && v > Lr) {
                        int p = atomicAdd(&ccnt[orow], 1);
                        if (p < CAP) {
                            cv[(size_t)orow*CAP + p] = v;
                            ci[(size_t)orow*CAP + p] = chunk_start + ocol;
                        }
                    }
                }
            }
    }
}

// ---------------- per-row top-200 superset selection (radix, chunk0 only) ----------------
__global__ __launch_bounds__(256) void select_topk(
    const float* __restrict__ sims, int sstride, int chunk_start, int cvalid,
    const float* __restrict__ pv, const int* __restrict__ pi, const int* __restrict__ pc,
    float* __restrict__ nv, int* __restrict__ ni, int* __restrict__ nc, int have_prev)
{
    __shared__ int hist[2048];
    __shared__ float bbv[BBCAP];
    __shared__ int bbi[BBCAP];
    __shared__ int s_binB, s_above, s_ccnt, s_bcnt, s_binB2;
    const int tid = threadIdx.x;
    const int r = blockIdx.x;
    const int pcnt = have_prev ? pc[r] : 0;
    const int total = cvalid + pcnt;
    const float* srow = sims + (size_t)r * sstride;
    const float* pvr = pv + (size_t)r * CAP;
    const int*   pir = pi + (size_t)r * CAP;

    for (int i = tid; i < 2048; i += 256) hist[i] = 0;
    if (tid == 0) { s_ccnt = 0; s_bcnt = 0; }
    __syncthreads();

    for (int i = tid; i < total; i += 256) {
        float v = (i < cvalid) ? srow[i] : pvr[i - cvalid];
        atomicAdd(&hist[fkey(v) >> 21], 1);
    }
    __syncthreads();
    if (tid == 0) {
        int cum = 0, b = 2047;
        for (; b > 0; --b) {
            if (cum + hist[b] >= MAXK) break;
            cum += hist[b];
        }
        s_binB = b; s_above = cum;
    }
    __syncthreads();
    const int binB = s_binB;

    for (int i = tid; i < total; i += 256) {
        float v; int idx;
        if (i < cvalid) { v = srow[i]; idx = chunk_start + i; }
        else { v = pvr[i - cvalid]; idx = pir[i - cvalid]; }
        int b = (int)(fkey(v) >> 21);
        if (b > binB) {
            int p = atomicAdd(&s_ccnt, 1);
            if (p < CAP) { nv[(size_t)r*CAP + p] = v; ni[(size_t)r*CAP + p] = idx; }
        } else if (b == binB) {
            int p = atomicAdd(&s_bcnt, 1);
            if (p < BBCAP) { bbv[p] = v; bbi[p] = idx; }
        }
    }
    __syncthreads();
    const int bcnt = min(s_bcnt, BBCAP);
    const int need = MAXK - s_above;

    for (int i = tid; i < 2048; i += 256) hist[i] = 0;
    __syncthreads();
    for (int i = tid; i < bcnt; i += 256)
        atomicAdd(&hist[(fkey(bbv[i]) >> 10) & 0x7FF], 1);
    __syncthreads();
    if (tid == 0) {
        int cum = 0, b = 2047;
        for (; b > 0; --b) {
            if (cum + hist[b] >= need) break;
            cum += hist[b];
        }
        s_binB2 = b;
    }
    __syncthreads();
    const int binB2 = s_binB2;
    for (int i = tid; i < bcnt; i += 256) {
        int sub = (int)((fkey(bbv[i]) >> 10) & 0x7FF);
        if (sub >= binB2) {
            int p = atomicAdd(&s_ccnt, 1);
            if (p < CAP) { nv[(size_t)r*CAP + p] = bbv[i]; ni[(size_t)r*CAP + p] = bbi[i]; }
        }
    }
    __syncthreads();
    if (tid == 0) nc[r] = min(s_ccnt, CAP);
}

// ---------------- sort candidate list, trim to 200, refresh threshold L ----------------
__global__ __launch_bounds__(256) void sort_trim(
    float* __restrict__ cv, int* __restrict__ ci, int* __restrict__ cc,
    float* __restrict__ L)
{
    __shared__ float sval[CAP];
    __shared__ int   sidx[CAP];
    const int tid = threadIdx.x;
    const int r = blockIdx.x;
    const int M = min(cc[r], CAP);

    for (int i = tid; i < CAP; i += 256) {
        if (i < M) { sval[i] = cv[(size_t)r*CAP + i]; sidx[i] = ci[(size_t)r*CAP + i]; }
        else { sval[i] = -FLT_MAX; sidx[i] = 0x7FFFFFFF; }
    }
    __syncthreads();
    for (int k = 2; k <= CAP; k <<= 1) {
        for (int j = k >> 1; j > 0; j >>= 1) {
            for (int i = tid; i < CAP; i += 256) {
                int l = i ^ j;
                if (l > i) {
                    float av = sval[i], bv = sval[l];
                    int ai = sidx[i], bi = sidx[l];
                    bool iGTl = (av > bv) || (av == bv && ai < bi);
                    bool sw = ((i & k) == 0) ? (!iGTl) : iGTl;
                    if (sw) { sval[i] = bv; sval[l] = av; sidx[i] = bi; sidx[l] = ai; }
                }
            }
            __syncthreads();
        }
    }
    for (int i = tid; i < MAXK; i += 256) {
        cv[(size_t)r*CAP + i] = sval[i];
        ci[(size_t)r*CAP + i] = sidx[i];
    }
    if (tid == 0) {
        if (M >= MAXK) { cc[r] = MAXK; L[r] = sval[MAXK-1]; }
        else cc[r] = M;
    }
}

// ---------------- final: sort, softmax over top-200, cumulative scatter 4 slabs ----------------
__global__ __launch_bounds__(256) void finalize_knn(
    const float* __restrict__ cv, const int* __restrict__ ci, const int* __restrict__ cc,
    const int* __restrict__ labels, float* __restrict__ out)
{
    __shared__ float sval[CAP];
    __shared__ int   sidx[CAP];
    __shared__ float cls[NCLS];
    __shared__ float s_sum;
    const int tid = threadIdx.x;
    const int r = blockIdx.x;
    const int M = min(cc[r], CAP);

    for (int i = tid; i < CAP; i += 256) {
        if (i < M) { sval[i] = cv[(size_t)r*CAP + i]; sidx[i] = ci[(size_t)r*CAP + i]; }
        else { sval[i] = -FLT_MAX; sidx[i] = 0x7FFFFFFF; }
    }
    __syncthreads();
    for (int k = 2; k <= CAP; k <<= 1) {
        for (int j = k >> 1; j > 0; j >>= 1) {
            for (int i = tid; i < CAP; i += 256) {
                int l = i ^ j;
                if (l > i) {
                    float av = sval[i], bv = sval[l];
                    int ai = sidx[i], bi = sidx[l];
                    bool iGTl = (av > bv) || (av == bv && ai < bi);
                    bool sw = ((i & k) == 0) ? (!iGTl) : iGTl;
                    if (sw) { sval[i] = bv; sval[l] = av; sidx[i] = bi; sidx[l] = ai; }
                }
            }
            __syncthreads();
        }
    }

    float mx = sval[0];
    if (tid == 0) s_sum = 0.f;
    __syncthreads();
    float part = 0.f;
    for (int i = tid; i < MAXK; i += 256) {
        float e = expf((sval[i] - mx) * INV_T);
        sval[i] = e;
        part += e;
    }
    atomicAdd(&s_sum, part);
    __syncthreads();
    float inv = 1.f / s_sum;
    for (int i = tid; i < MAXK; i += 256) {
        sval[i] *= inv;
        sidx[i] = labels[sidx[i]];
    }
    for (int c = tid; c < NCLS; c += 256) cls[c] = 0.f;
    __syncthreads();

    const int KS[4] = {10, 20, 100, 200};
    int prev = 0;
    for (int s = 0; s < 4; ++s) {
        for (int i = prev + tid; i < KS[s]; i += 256)
            atomicAdd(&cls[sidx[i]], sval[i]);
        __syncthreads();
        float* o = out + ((size_t)s * NROWS + r) * NCLS;
        for (int c = tid; c < NCLS; c += 256) o[c] = cls[c];
        __syncthreads();
        prev = KS[s];
    }
}

// ---------------- host launcher ----------------
static inline int imin(int a, int b) { return a < b ? a : b; }

extern "C" void kernel_launch(void* const* d_in, const int* in_sizes, int n_in,
                              void* d_out, int out_size, void* d_ws, size_t ws_size,
                              hipStream_t stream)
{
    const float* A = (const float*)d_in[0];       // [512,1024]
    const float* B = (const float*)d_in[1];       // [100000,1024]
    const int* labels = (const int*)d_in[2];      // [100000]
    float* out = (float*)d_out;                   // [4,512,1000] f32

    char* ws = (char*)d_ws;
    size_t off = 0;
    auto carve = [&](size_t bytes) -> void* {
        void* p = ws + off;
        off = (off + bytes + 255) & ~(size_t)255;
        return p;
    };
    _Float16* Ahi = (_Float16*)carve((size_t)NROWS * DIM * 2);
    _Float16* Alo = (_Float16*)carve((size_t)NROWS * DIM * 2);
    float* cv = (float*)carve((size_t)NROWS * CAP * 4);
    int*   ci = (int*)carve((size_t)NROWS * CAP * 4);
    int*   cc = (int*)carve((size_t)NROWS * 4);
    float* L  = (float*)carve((size_t)NROWS * 4);
    const int C0MAX = 8192;
    float* sims = (float*)carve((size_t)NROWS * C0MAX * 4);

    size_t remain = (ws_size > off) ? (ws_size - off) : 0;
    long long capll = (long long)(remain / ((size_t)DIM * 4));   // Bhi+Blo bytes/col
    int cap_cols = (capll > NTRAIN + 127) ? (NTRAIN + 127) : (int)capll;
    cap_cols &= ~127;
    if (cap_cols < 256) cap_cols = 256;
    _Float16* Bh = (_Float16*)carve((size_t)cap_cols * DIM * 2);
    _Float16* Bl = (_Float16*)carve((size_t)cap_cols * DIM * 2);

    // split A once
    convert_split<<<512, 256, 0, stream>>>(A, Ahi, Alo, (long long)NROWS * DIM);

    int start = 0, first = 1;
    while (start < NTRAIN) {
        int c = first ? imin(C0MAX, cap_cols) : imin(start, cap_cols);
        if (c > NTRAIN - start) c = NTRAIN - start;
        int cpad = (c + 127) & ~127;
        long long nconv = (long long)c * DIM;
        int nblk = (int)((nconv / 1024 < 4096) ? nconv / 1024 : 4096);
        if (nblk < 1) nblk = 1;
        convert_split<<<nblk, 256, 0, stream>>>(B + (size_t)start * DIM, Bh, Bl, nconv);

        int ntile = cpad / 128;
        gemm_f16x3<<<4 * ntile, 256, 0, stream>>>(Ahi, Alo, Bh, Bl,
            sims, cpad, c, start, first ? 0 : 1, L, cv, ci, cc);

        if (first) {
            select_topk<<<NROWS, 256, 0, stream>>>(sims, cpad, 0, c,
                cv, ci, cc, cv, ci, cc, 0);
            first = 0;
        }
        start += c;
        if (start < NTRAIN)
            sort_trim<<<NROWS, 256, 0, stream>>>(cv, ci, cc, L);
    }
    finalize_knn<<<NROWS, 256, 0, stream>>>(cv, ci, cc, labels, out);
}